// Round 2
// baseline (2537.001 us; speedup 1.0000x reference)
//
#include <hip/hip_runtime.h>
#include <hip/hip_bf16.h>
#include <math.h>

#define NQ 8192
#define NA 32768
#define NE 500000
#define F_IN 128
#define E_E2Q 131072
#define E_E2E 800000
#define E_E2A 262144
#define E_Q2A 32768
#define N_POS 8192
#define N_NEG 24576

#define NT_TOTAL (NQ + NA + NE)                      // 540960
#define E_TOTAL (E_E2Q + E_E2E + E_E2A + E_Q2A)      // 1225984

// ---------------- utility ----------------

__device__ inline void atomicMaxF(float* addr, float v) {
  if (v >= 0.f) atomicMax((int*)addr, __float_as_int(v));
  else atomicMin((unsigned int*)addr, __float_as_uint(v));
}

__global__ void fill_kernel(float* __restrict__ p, float v, size_t n) {
  size_t i = (size_t)blockIdx.x * blockDim.x + threadIdx.x;
  size_t stride = (size_t)gridDim.x * blockDim.x;
  for (; i < n; i += stride) p[i] = v;
}

// ---------------- tiled fp32 GEMM: C = act(A@B + bias), optional skip blend ----------------
// A: [M,K] lda, B: [K,N] ldb, C: [M,N] ldc. act: 0=none, 1=relu.
// If res != nullptr: C = g*val + (1-g)*res, g = sigmoid(skip_ptr[skip_idx]).

__global__ __launch_bounds__(256) void gemm_tile(
    const float* __restrict__ A, int lda,
    const float* __restrict__ B, int ldb,
    const float* __restrict__ bias,
    float* __restrict__ Cmat, int ldc,
    int M, int N, int K, int act,
    const float* __restrict__ res, int ldres,
    const float* __restrict__ skip_ptr, int skip_idx)
{
  __shared__ __align__(16) float As[16][68];
  __shared__ __align__(16) float Bs[16][68];
  int tid = threadIdx.x;
  int tx = tid & 15, ty = tid >> 4;
  int row0 = blockIdx.x * 64, col0 = blockIdx.y * 64;
  float acc[4][4] = {};
  for (int k0 = 0; k0 < K; k0 += 16) {
#pragma unroll
    for (int l = 0; l < 4; ++l) {
      int idx = tid + l * 256;
      int m = idx >> 4, kk = idx & 15;
      int gr = row0 + m;
      As[kk][m] = (gr < M) ? A[(size_t)gr * lda + k0 + kk] : 0.f;
      int kb = idx >> 6, n = idx & 63;
      Bs[kb][n] = B[(size_t)(k0 + kb) * ldb + col0 + n];
    }
    __syncthreads();
#pragma unroll
    for (int kk = 0; kk < 16; ++kk) {
      float4 av = *(const float4*)&As[kk][ty * 4];
      float4 bv = *(const float4*)&Bs[kk][tx * 4];
      float a[4] = {av.x, av.y, av.z, av.w};
      float b[4] = {bv.x, bv.y, bv.z, bv.w};
#pragma unroll
      for (int i = 0; i < 4; ++i)
#pragma unroll
        for (int j = 0; j < 4; ++j)
          acc[i][j] = fmaf(a[i], b[j], acc[i][j]);
    }
    __syncthreads();
  }
  float g = 1.f;
  if (skip_ptr) g = 1.f / (1.f + expf(-skip_ptr[skip_idx]));
#pragma unroll
  for (int i = 0; i < 4; ++i) {
    int row = row0 + ty * 4 + i;
    if (row >= M) continue;
#pragma unroll
    for (int j = 0; j < 4; ++j) {
      int col = col0 + tx * 4 + j;
      float v = acc[i][j] + bias[col];
      if (act == 1) v = fmaxf(v, 0.f);
      if (res) v = g * v + (1.f - g) * res[(size_t)row * ldres + col];
      Cmat[(size_t)row * ldc + col] = v;
    }
  }
}

// ---------------- BN stats (sum + sumsq per column) ----------------

__global__ __launch_bounds__(256) void bn_stats(const float* __restrict__ y, int Nrows,
                                                float* __restrict__ stats) {
  __shared__ float sh1[256], sh2[256];
  int tid = threadIdx.x;
  int col = tid & 63;
  int q = tid >> 6;
  float s1 = 0.f, s2 = 0.f;
  for (int row = blockIdx.x * 4 + q; row < Nrows; row += gridDim.x * 4) {
    float v = y[(size_t)row * 64 + col];
    s1 += v;
    s2 += v * v;
  }
  sh1[tid] = s1;
  sh2[tid] = s2;
  __syncthreads();
  if (tid < 64) {
    s1 = sh1[tid] + sh1[tid + 64] + sh1[tid + 128] + sh1[tid + 192];
    s2 = sh2[tid] + sh2[tid + 64] + sh2[tid + 128] + sh2[tid + 192];
    atomicAdd(&stats[col], s1);
    atomicAdd(&stats[64 + col], s2);
  }
}

__global__ void bn_apply(const float* __restrict__ y, const float* __restrict__ stats,
                         const float* __restrict__ gamma, const float* __restrict__ beta,
                         float* __restrict__ h, int Nrows) {
  size_t total = (size_t)Nrows * 64;
  size_t stride = (size_t)gridDim.x * blockDim.x;
  float invN = 1.f / (float)Nrows;
  for (size_t i = (size_t)blockIdx.x * blockDim.x + threadIdx.x; i < total; i += stride) {
    int c = (int)(i & 63);
    float mu = stats[c] * invN;
    float var = stats[64 + c] * invN - mu * mu;
    float rs = rsqrtf(var + 1e-5f);
    h[i] = gamma[c] * (y[i] - mu) * rs + beta[c];
  }
}

// ---------------- edge pass 1: scores + segment max ----------------
// group of 32 lanes per (edge, head); 4 edges x 2 heads per 256-block.

__global__ __launch_bounds__(256) void edge_score(
    const int* __restrict__ esrc, const int* __restrict__ edst, int E,
    const float* __restrict__ kqv_s, const float* __restrict__ kqv_d,
    const float* __restrict__ Ak, const float* __restrict__ prel,
    float* __restrict__ sc, float* __restrict__ mbuf)
{
  __shared__ float Ash[2048];
  int tid = threadIdx.x;
  for (int i = tid; i < 2048; i += 256) Ash[i] = Ak[i];
  __syncthreads();
  int lane = tid & 31;
  int grp = tid >> 5;
  int e = blockIdx.x * 4 + (grp >> 1);
  int h = grp & 1;
  if (e >= E) return;
  int s = esrc[e], d = edst[e];
  const float* kp = kqv_s + (size_t)s * 192 + h * 32;
  const float* qp = kqv_d + (size_t)d * 192 + 64 + h * 32;
  const float* Ah = Ash + h * 1024;
  float kr = 0.f;
#pragma unroll 8
  for (int dd = 0; dd < 32; ++dd) kr = fmaf(kp[dd], Ah[dd * 32 + lane], kr);
  float p = qp[lane] * kr;
#pragma unroll
  for (int off = 16; off > 0; off >>= 1) p += __shfl_xor(p, off, 32);
  if (lane == 0) {
    float v = p * prel[h] * 0.17677669529663687f;  // 1/sqrt(32)
    sc[(size_t)e * 2 + h] = v;
    atomicMaxF(&mbuf[(size_t)d * 2 + h], v);
  }
}

// ---------------- edge pass 2: exp-weighted value scatter ----------------

__global__ __launch_bounds__(256) void edge_accum(
    const int* __restrict__ esrc, const int* __restrict__ edst, int E,
    const float* __restrict__ kqv_s,
    const float* __restrict__ Av,
    const float* __restrict__ sc, const float* __restrict__ mbuf,
    float* __restrict__ sbuf, float* __restrict__ agg)
{
  __shared__ float Ash[2048];
  int tid = threadIdx.x;
  for (int i = tid; i < 2048; i += 256) Ash[i] = Av[i];
  __syncthreads();
  int lane = tid & 31;
  int grp = tid >> 5;
  int e = blockIdx.x * 4 + (grp >> 1);
  int h = grp & 1;
  if (e >= E) return;
  int s = esrc[e], d = edst[e];
  const float* vp = kqv_s + (size_t)s * 192 + 128 + h * 32;
  const float* Ah = Ash + h * 1024;
  float vr = 0.f;
#pragma unroll 8
  for (int dd = 0; dd < 32; ++dd) vr = fmaf(vp[dd], Ah[dd * 32 + lane], vr);
  float w = expf(sc[(size_t)e * 2 + h] - mbuf[(size_t)d * 2 + h]);
  if (lane == 0) atomicAdd(&sbuf[(size_t)d * 2 + h], w);
  atomicAdd(&agg[(size_t)d * 64 + h * 32 + lane], vr * w);
}

// ---------------- finalize: normalize + exact GELU (in place) ----------------

__global__ void finalize_gelu(float* __restrict__ agg, const float* __restrict__ sbuf,
                              size_t total) {
  size_t stride = (size_t)gridDim.x * blockDim.x;
  for (size_t i = (size_t)blockIdx.x * blockDim.x + threadIdx.x; i < total; i += stride) {
    size_t n = i >> 6;
    int c = (int)(i & 63);
    float sv = sbuf[n * 2 + (c >> 5)];
    float v = (sv > 0.f) ? agg[i] / sv : 0.f;
    agg[i] = 0.5f * v * (1.f + erff(v * 0.70710678118654752f));
  }
}

// ---------------- final predictions ----------------

__global__ void pred_kernel(const int* __restrict__ qi, const int* __restrict__ ai, int Np,
                            const float* __restrict__ zq, const float* __restrict__ za,
                            float* __restrict__ outp) {
  int i = blockIdx.x * blockDim.x + threadIdx.x;
  if (i >= Np) return;
  const float4* a = (const float4*)(zq + (size_t)qi[i] * 64);
  const float4* b = (const float4*)(za + (size_t)ai[i] * 64);
  float ssum = 0.f;
#pragma unroll
  for (int j = 0; j < 16; ++j) {
    float4 x = a[j], y = b[j];
    ssum += x.x * y.x + x.y * y.y + x.z * y.z + x.w * y.w;
  }
  outp[i] = ssum;
}

// ---------------- host launch ----------------

extern "C" void kernel_launch(void* const* d_in, const int* in_sizes, int n_in,
                              void* d_out, int out_size, void* d_ws, size_t ws_size,
                              hipStream_t stream) {
  const float* xq = (const float*)d_in[0];
  const float* xa = (const float*)d_in[1];
  const float* xe = (const float*)d_in[2];
  const int* e_e2q = (const int*)d_in[3];
  const int* e_e2e = (const int*)d_in[4];
  const int* e_e2a = (const int*)d_in[5];
  const int* e_q2a = (const int*)d_in[6];
  const int* pos_idx = (const int*)d_in[7];
  const int* neg_idx = (const int*)d_in[8];
  const float* W_in = (const float*)d_in[9];
  const float* b_in = (const float*)d_in[10];
  const float* bn_gamma = (const float*)d_in[11];
  const float* bn_beta = (const float*)d_in[12];
  const float* W_kqv = (const float*)d_in[13];
  const float* b_kqv = (const float*)d_in[14];
  const float* A_k = (const float*)d_in[15];
  const float* A_v = (const float*)d_in[16];
  const float* p_rel = (const float*)d_in[17];
  const float* W_out = (const float*)d_in[18];
  const float* b_out = (const float*)d_in[19];
  const float* skip = (const float*)d_in[20];
  float* out = (float*)d_out;

  float* ws = (float*)d_ws;
  size_t off = 0;
  float* y_all = ws;             off += (size_t)NT_TOTAL * 64;   // reused as agg
  float* h_all = ws + off;       off += (size_t)NT_TOTAL * 64;
  float* kqv_all = ws + off;     off += (size_t)NT_TOTAL * 192;
  float* sc_all = ws + off;      off += (size_t)E_TOTAL * 2;
  float* m_all = ws + off;       off += (size_t)NT_TOTAL * 2;
  float* s_all = ws + off;       off += (size_t)NT_TOTAL * 2;
  float* stats = ws + off;       off += 3 * 128;

  const int Ns[3] = {NQ, NA, NE};
  const float* xs[3] = {xq, xa, xe};
  float* ybase[3] = {y_all, y_all + (size_t)NQ * 64, y_all + (size_t)(NQ + NA) * 64};
  float* hbase[3] = {h_all, h_all + (size_t)NQ * 64, h_all + (size_t)(NQ + NA) * 64};
  float* kqvbase[3] = {kqv_all, kqv_all + (size_t)NQ * 192, kqv_all + (size_t)(NQ + NA) * 192};
  float* mbase[3] = {m_all, m_all + (size_t)NQ * 2, m_all + (size_t)(NQ + NA) * 2};
  float* sbase[3] = {s_all, s_all + (size_t)NQ * 2, s_all + (size_t)(NQ + NA) * 2};
  float* zq_out = out + (N_POS + N_NEG);
  float* zbase[3] = {zq_out, zq_out + (size_t)NQ * 64, zq_out + (size_t)(NQ + NA) * 64};

  // zero BN stats accumulators
  fill_kernel<<<dim3(8), dim3(256), 0, stream>>>(stats, 0.f, (size_t)(3 * 128));

  // input proj + relu, BN stats, BN apply
  for (int t = 0; t < 3; ++t) {
    dim3 g1((Ns[t] + 63) / 64, 1);
    gemm_tile<<<g1, 256, 0, stream>>>(xs[t], F_IN, W_in + (size_t)t * F_IN * 64, 64,
                                      b_in + t * 64,
                                      ybase[t], 64, Ns[t], 64, F_IN, 1, nullptr, 0, nullptr, 0);
    bn_stats<<<dim3(512), dim3(256), 0, stream>>>(ybase[t], Ns[t], stats + t * 128);
    int total = Ns[t] * 64;
    int gsz = (total + 255) / 256;
    if (gsz > 2048) gsz = 2048;
    bn_apply<<<dim3(gsz), dim3(256), 0, stream>>>(ybase[t], stats + t * 128, bn_gamma + t * 64,
                                                  bn_beta + t * 64, hbase[t], Ns[t]);
  }

  // kqv projection
  for (int t = 0; t < 3; ++t) {
    dim3 g2((Ns[t] + 63) / 64, 3);
    gemm_tile<<<g2, 256, 0, stream>>>(hbase[t], 64, W_kqv + (size_t)t * 64 * 192, 192,
                                      b_kqv + t * 192,
                                      kqvbase[t], 192, Ns[t], 192, 64, 0, nullptr, 0, nullptr, 0);
  }

  // init segment buffers (y_all reused as agg — y is dead after bn_apply)
  fill_kernel<<<dim3(64), dim3(256), 0, stream>>>(m_all, -INFINITY, (size_t)NT_TOTAL * 2);
  fill_kernel<<<dim3(64), dim3(256), 0, stream>>>(s_all, 0.f, (size_t)NT_TOTAL * 2);
  fill_kernel<<<dim3(2048), dim3(256), 0, stream>>>(y_all, 0.f, (size_t)NT_TOTAL * 64);

  struct Rel { const int* ei; int E; int st; int dt; };
  Rel rels[4] = {{e_e2q, E_E2Q, 2, 0}, {e_e2e, E_E2E, 2, 2},
                 {e_e2a, E_E2A, 2, 1}, {e_q2a, E_Q2A, 0, 1}};

  // pass 1: scores + segment max
  size_t scoff = 0;
  for (int r = 0; r < 4; ++r) {
    const int* src = rels[r].ei;
    const int* dst = src + rels[r].E;
    edge_score<<<dim3((rels[r].E + 3) / 4), dim3(256), 0, stream>>>(
        src, dst, rels[r].E, kqvbase[rels[r].st], kqvbase[rels[r].dt],
        A_k + (size_t)r * 2048, p_rel + r * 2, sc_all + scoff, mbase[rels[r].dt]);
    scoff += (size_t)rels[r].E * 2;
  }

  // pass 2: exp-weighted scatter
  scoff = 0;
  for (int r = 0; r < 4; ++r) {
    const int* src = rels[r].ei;
    const int* dst = src + rels[r].E;
    float* aggb = ybase[rels[r].dt];
    edge_accum<<<dim3((rels[r].E + 3) / 4), dim3(256), 0, stream>>>(
        src, dst, rels[r].E, kqvbase[rels[r].st],
        A_v + (size_t)r * 2048, sc_all + scoff, mbase[rels[r].dt],
        sbase[rels[r].dt], aggb);
    scoff += (size_t)rels[r].E * 2;
  }

  // normalize + gelu (in place over all types: agg/s layouts are contiguous)
  finalize_gelu<<<dim3(2048), dim3(256), 0, stream>>>(y_all, s_all, (size_t)NT_TOTAL * 64);

  // out projection + skip blend -> z in d_out
  for (int t = 0; t < 3; ++t) {
    dim3 g3((Ns[t] + 63) / 64, 1);
    gemm_tile<<<g3, 256, 0, stream>>>(ybase[t], 64, W_out + (size_t)t * 64 * 64, 64,
                                      b_out + t * 64,
                                      zbase[t], 64, Ns[t], 64, 64, 0, hbase[t], 64, skip, t);
  }

  // predictions
  pred_kernel<<<dim3((N_POS + 255) / 256), dim3(256), 0, stream>>>(
      pos_idx, pos_idx + N_POS, N_POS, zbase[0], zbase[1], out);
  pred_kernel<<<dim3((N_NEG + 255) / 256), dim3(256), 0, stream>>>(
      neg_idx, neg_idx + N_NEG, N_NEG, zbase[0], zbase[1], out + N_POS);
}

// Round 3
// 1939.195 us; speedup vs baseline: 1.3083x; 1.3083x over previous
//
#include <hip/hip_runtime.h>
#include <hip/hip_bf16.h>
#include <math.h>

#define NQ 8192
#define NA 32768
#define NE 500000
#define F_IN 128
#define E_E2Q 131072
#define E_E2E 800000
#define E_E2A 262144
#define E_Q2A 32768
#define N_POS 8192
#define N_NEG 24576

#define NT_TOTAL (NQ + NA + NE)                      // 540960
#define E_TOTAL (E_E2Q + E_E2E + E_E2A + E_Q2A)      // 1225984

// ---------------- utility ----------------

__global__ void fill_kernel(float* __restrict__ p, float v, size_t n) {
  size_t i = (size_t)blockIdx.x * blockDim.x + threadIdx.x;
  size_t stride = (size_t)gridDim.x * blockDim.x;
  for (; i < n; i += stride) p[i] = v;
}

// ---------------- tiled fp32 GEMM: C = act(A@B + bias), optional skip blend ----------------

__global__ __launch_bounds__(256) void gemm_tile(
    const float* __restrict__ A, int lda,
    const float* __restrict__ B, int ldb,
    const float* __restrict__ bias,
    float* __restrict__ Cmat, int ldc,
    int M, int N, int K, int act,
    const float* __restrict__ res, int ldres,
    const float* __restrict__ skip_ptr, int skip_idx)
{
  __shared__ __align__(16) float As[16][68];
  __shared__ __align__(16) float Bs[16][68];
  int tid = threadIdx.x;
  int tx = tid & 15, ty = tid >> 4;
  int row0 = blockIdx.x * 64, col0 = blockIdx.y * 64;
  float acc[4][4] = {};
  for (int k0 = 0; k0 < K; k0 += 16) {
#pragma unroll
    for (int l = 0; l < 4; ++l) {
      int idx = tid + l * 256;
      int m = idx >> 4, kk = idx & 15;
      int gr = row0 + m;
      As[kk][m] = (gr < M) ? A[(size_t)gr * lda + k0 + kk] : 0.f;
      int kb = idx >> 6, n = idx & 63;
      Bs[kb][n] = B[(size_t)(k0 + kb) * ldb + col0 + n];
    }
    __syncthreads();
#pragma unroll
    for (int kk = 0; kk < 16; ++kk) {
      float4 av = *(const float4*)&As[kk][ty * 4];
      float4 bv = *(const float4*)&Bs[kk][tx * 4];
      float a[4] = {av.x, av.y, av.z, av.w};
      float b[4] = {bv.x, bv.y, bv.z, bv.w};
#pragma unroll
      for (int i = 0; i < 4; ++i)
#pragma unroll
        for (int j = 0; j < 4; ++j)
          acc[i][j] = fmaf(a[i], b[j], acc[i][j]);
    }
    __syncthreads();
  }
  float g = 1.f;
  if (skip_ptr) g = 1.f / (1.f + expf(-skip_ptr[skip_idx]));
#pragma unroll
  for (int i = 0; i < 4; ++i) {
    int row = row0 + ty * 4 + i;
    if (row >= M) continue;
#pragma unroll
    for (int j = 0; j < 4; ++j) {
      int col = col0 + tx * 4 + j;
      float v = acc[i][j] + bias[col];
      if (act == 1) v = fmaxf(v, 0.f);
      if (res) v = g * v + (1.f - g) * res[(size_t)row * ldres + col];
      Cmat[(size_t)row * ldc + col] = v;
    }
  }
}

// ---------------- BN stats (sum + sumsq per column) ----------------

__global__ __launch_bounds__(256) void bn_stats(const float* __restrict__ y, int Nrows,
                                                float* __restrict__ stats) {
  __shared__ float sh1[256], sh2[256];
  int tid = threadIdx.x;
  int col = tid & 63;
  int q = tid >> 6;
  float s1 = 0.f, s2 = 0.f;
  for (int row = blockIdx.x * 4 + q; row < Nrows; row += gridDim.x * 4) {
    float v = y[(size_t)row * 64 + col];
    s1 += v;
    s2 += v * v;
  }
  sh1[tid] = s1;
  sh2[tid] = s2;
  __syncthreads();
  if (tid < 64) {
    s1 = sh1[tid] + sh1[tid + 64] + sh1[tid + 128] + sh1[tid + 192];
    s2 = sh2[tid] + sh2[tid + 64] + sh2[tid + 128] + sh2[tid + 192];
    atomicAdd(&stats[col], s1);
    atomicAdd(&stats[64 + col], s2);
  }
}

__global__ void bn_apply(const float* __restrict__ y, const float* __restrict__ stats,
                         const float* __restrict__ gamma, const float* __restrict__ beta,
                         float* __restrict__ h, int Nrows) {
  size_t total = (size_t)Nrows * 64;
  size_t stride = (size_t)gridDim.x * blockDim.x;
  float invN = 1.f / (float)Nrows;
  for (size_t i = (size_t)blockIdx.x * blockDim.x + threadIdx.x; i < total; i += stride) {
    int c = (int)(i & 63);
    float mu = stats[c] * invN;
    float var = stats[64 + c] * invN - mu * mu;
    float rs = rsqrtf(var + 1e-5f);
    h[i] = gamma[c] * (y[i] - mu) * rs + beta[c];
  }
}

// ---------------- fused edge pass: transform + score + exp + scatter ----------------
// One wave (64 lanes) per edge, both heads (lane = h*32 + f).
// A_k / A_v columns live in registers (loaded once, amortized by grid-stride loop).
// No segment-max: scores are O(1) (BN-normalized inputs), exp is safe in fp32 and
// softmax is shift-invariant, so result matches the reference.

__global__ __launch_bounds__(256) void edge_fused(
    const int* __restrict__ esrc, const int* __restrict__ edst, int E,
    const float* __restrict__ kqv_s, const float* __restrict__ kqv_d,
    const float* __restrict__ Ak, const float* __restrict__ Av,
    const float* __restrict__ prel,
    float* __restrict__ sbuf, float* __restrict__ agg)
{
  int lane = threadIdx.x & 63;
  int h = lane >> 5;
  int f = lane & 31;
  float ak[32], av[32];
#pragma unroll
  for (int dd = 0; dd < 32; ++dd) {
    ak[dd] = Ak[h * 1024 + dd * 32 + f];
    av[dd] = Av[h * 1024 + dd * 32 + f];
  }
  float pr = prel[h] * 0.17677669529663687f;  // p_rel / sqrt(32)

  int wid = (int)((blockIdx.x * blockDim.x + threadIdx.x) >> 6);
  int nw = (int)((gridDim.x * blockDim.x) >> 6);
  for (int e = wid; e < E; e += nw) {
    int s = esrc[e], d = edst[e];
    float kval = kqv_s[(size_t)s * 192 + lane];        // k, both heads (256B coalesced)
    float vval = kqv_s[(size_t)s * 192 + 128 + lane];  // v
    float qval = kqv_d[(size_t)d * 192 + 64 + lane];   // q
    float kr = 0.f, vr = 0.f;
#pragma unroll
    for (int dd = 0; dd < 32; ++dd) {
      kr = fmaf(__shfl(kval, dd, 32), ak[dd], kr);
      vr = fmaf(__shfl(vval, dd, 32), av[dd], vr);
    }
    float p = qval * kr;
#pragma unroll
    for (int off = 16; off > 0; off >>= 1) p += __shfl_xor(p, off, 32);
    float w = expf(p * pr);
    atomicAdd(&agg[(size_t)d * 64 + lane], vr * w);
    if (f == 0) atomicAdd(&sbuf[(size_t)d * 2 + h], w);
  }
}

// ---------------- finalize: normalize + exact GELU (in place) ----------------

__global__ void finalize_gelu(float* __restrict__ agg, const float* __restrict__ sbuf,
                              size_t total) {
  size_t stride = (size_t)gridDim.x * blockDim.x;
  for (size_t i = (size_t)blockIdx.x * blockDim.x + threadIdx.x; i < total; i += stride) {
    size_t n = i >> 6;
    int c = (int)(i & 63);
    float sv = sbuf[n * 2 + (c >> 5)];
    float v = (sv > 0.f) ? agg[i] / sv : 0.f;
    agg[i] = 0.5f * v * (1.f + erff(v * 0.70710678118654752f));
  }
}

// ---------------- final predictions ----------------

__global__ void pred_kernel(const int* __restrict__ qi, const int* __restrict__ ai, int Np,
                            const float* __restrict__ zq, const float* __restrict__ za,
                            float* __restrict__ outp) {
  int i = blockIdx.x * blockDim.x + threadIdx.x;
  if (i >= Np) return;
  const float4* a = (const float4*)(zq + (size_t)qi[i] * 64);
  const float4* b = (const float4*)(za + (size_t)ai[i] * 64);
  float ssum = 0.f;
#pragma unroll
  for (int j = 0; j < 16; ++j) {
    float4 x = a[j], y = b[j];
    ssum += x.x * y.x + x.y * y.y + x.z * y.z + x.w * y.w;
  }
  outp[i] = ssum;
}

// ---------------- host launch ----------------

extern "C" void kernel_launch(void* const* d_in, const int* in_sizes, int n_in,
                              void* d_out, int out_size, void* d_ws, size_t ws_size,
                              hipStream_t stream) {
  const float* xq = (const float*)d_in[0];
  const float* xa = (const float*)d_in[1];
  const float* xe = (const float*)d_in[2];
  const int* e_e2q = (const int*)d_in[3];
  const int* e_e2e = (const int*)d_in[4];
  const int* e_e2a = (const int*)d_in[5];
  const int* e_q2a = (const int*)d_in[6];
  const int* pos_idx = (const int*)d_in[7];
  const int* neg_idx = (const int*)d_in[8];
  const float* W_in = (const float*)d_in[9];
  const float* b_in = (const float*)d_in[10];
  const float* bn_gamma = (const float*)d_in[11];
  const float* bn_beta = (const float*)d_in[12];
  const float* W_kqv = (const float*)d_in[13];
  const float* b_kqv = (const float*)d_in[14];
  const float* A_k = (const float*)d_in[15];
  const float* A_v = (const float*)d_in[16];
  const float* p_rel = (const float*)d_in[17];
  const float* W_out = (const float*)d_in[18];
  const float* b_out = (const float*)d_in[19];
  const float* skip = (const float*)d_in[20];
  float* out = (float*)d_out;

  float* ws = (float*)d_ws;
  size_t off = 0;
  float* y_all = ws;             off += (size_t)NT_TOTAL * 64;   // reused as agg
  float* h_all = ws + off;       off += (size_t)NT_TOTAL * 64;
  float* kqv_all = ws + off;     off += (size_t)NT_TOTAL * 192;
  float* s_all = ws + off;       off += (size_t)NT_TOTAL * 2;
  float* stats = ws + off;       off += 3 * 128;

  const int Ns[3] = {NQ, NA, NE};
  const float* xs[3] = {xq, xa, xe};
  float* ybase[3] = {y_all, y_all + (size_t)NQ * 64, y_all + (size_t)(NQ + NA) * 64};
  float* hbase[3] = {h_all, h_all + (size_t)NQ * 64, h_all + (size_t)(NQ + NA) * 64};
  float* kqvbase[3] = {kqv_all, kqv_all + (size_t)NQ * 192, kqv_all + (size_t)(NQ + NA) * 192};
  float* sbase[3] = {s_all, s_all + (size_t)NQ * 2, s_all + (size_t)(NQ + NA) * 2};
  float* zq_out = out + (N_POS + N_NEG);
  float* zbase[3] = {zq_out, zq_out + (size_t)NQ * 64, zq_out + (size_t)(NQ + NA) * 64};

  // zero BN stats accumulators
  fill_kernel<<<dim3(8), dim3(256), 0, stream>>>(stats, 0.f, (size_t)(3 * 128));

  // input proj + relu, BN stats, BN apply
  for (int t = 0; t < 3; ++t) {
    dim3 g1((Ns[t] + 63) / 64, 1);
    gemm_tile<<<g1, 256, 0, stream>>>(xs[t], F_IN, W_in + (size_t)t * F_IN * 64, 64,
                                      b_in + t * 64,
                                      ybase[t], 64, Ns[t], 64, F_IN, 1, nullptr, 0, nullptr, 0);
    bn_stats<<<dim3(512), dim3(256), 0, stream>>>(ybase[t], Ns[t], stats + t * 128);
    int total = Ns[t] * 64;
    int gsz = (total + 255) / 256;
    if (gsz > 2048) gsz = 2048;
    bn_apply<<<dim3(gsz), dim3(256), 0, stream>>>(ybase[t], stats + t * 128, bn_gamma + t * 64,
                                                  bn_beta + t * 64, hbase[t], Ns[t]);
  }

  // kqv projection
  for (int t = 0; t < 3; ++t) {
    dim3 g2((Ns[t] + 63) / 64, 3);
    gemm_tile<<<g2, 256, 0, stream>>>(hbase[t], 64, W_kqv + (size_t)t * 64 * 192, 192,
                                      b_kqv + t * 192,
                                      kqvbase[t], 192, Ns[t], 192, 64, 0, nullptr, 0, nullptr, 0);
  }

  // init segment buffers (y_all reused as agg — y is dead after bn_apply)
  fill_kernel<<<dim3(64), dim3(256), 0, stream>>>(s_all, 0.f, (size_t)NT_TOTAL * 2);
  fill_kernel<<<dim3(2048), dim3(256), 0, stream>>>(y_all, 0.f, (size_t)NT_TOTAL * 64);

  struct Rel { const int* ei; int E; int st; int dt; };
  Rel rels[4] = {{e_e2q, E_E2Q, 2, 0}, {e_e2e, E_E2E, 2, 2},
                 {e_e2a, E_E2A, 2, 1}, {e_q2a, E_Q2A, 0, 1}};

  // fused edge pass (one traversal: transform + score + exp + scatter)
  for (int r = 0; r < 4; ++r) {
    const int* src = rels[r].ei;
    const int* dst = src + rels[r].E;
    int blocks = (rels[r].E + 3) / 4;
    if (blocks > 4096) blocks = 4096;
    edge_fused<<<dim3(blocks), dim3(256), 0, stream>>>(
        src, dst, rels[r].E, kqvbase[rels[r].st], kqvbase[rels[r].dt],
        A_k + (size_t)r * 2048, A_v + (size_t)r * 2048, p_rel + r * 2,
        sbase[rels[r].dt], ybase[rels[r].dt]);
  }

  // normalize + gelu (in place over all types: agg/s layouts are contiguous)
  finalize_gelu<<<dim3(2048), dim3(256), 0, stream>>>(y_all, s_all, (size_t)NT_TOTAL * 64);

  // out projection + skip blend -> z in d_out
  for (int t = 0; t < 3; ++t) {
    dim3 g3((Ns[t] + 63) / 64, 1);
    gemm_tile<<<g3, 256, 0, stream>>>(ybase[t], 64, W_out + (size_t)t * 64 * 64, 64,
                                      b_out + t * 64,
                                      zbase[t], 64, Ns[t], 64, 64, 0, hbase[t], 64, skip, t);
  }

  // predictions
  pred_kernel<<<dim3((N_POS + 255) / 256), dim3(256), 0, stream>>>(
      pos_idx, pos_idx + N_POS, N_POS, zbase[0], zbase[1], out);
  pred_kernel<<<dim3((N_NEG + 255) / 256), dim3(256), 0, stream>>>(
      neg_idx, neg_idx + N_NEG, N_NEG, zbase[0], zbase[1], out + N_POS);
}

// Round 4
// 1804.479 us; speedup vs baseline: 1.4059x; 1.0747x over previous
//
#include <hip/hip_runtime.h>
#include <hip/hip_bf16.h>
#include <math.h>

#define NQ 8192
#define NA 32768
#define NE 500000
#define F_IN 128
#define E_E2Q 131072
#define E_E2E 800000
#define E_E2A 262144
#define E_Q2A 32768
#define N_POS 8192
#define N_NEG 24576

#define NT_TOTAL (NQ + NA + NE)                      // 540960
#define E_TOTAL (E_E2Q + E_E2E + E_E2A + E_Q2A)      // 1225984
#define NBLK_SCAN ((NT_TOTAL + 1023) / 1024)         // 529

// unified node index space: [question: 0) [answer: NQ) [entity: NQ+NA)
#define BASE_Q 0
#define BASE_A NQ
#define BASE_E (NQ + NA)

// ---------------- utility ----------------

__global__ void fill_kernel(float* __restrict__ p, float v, size_t n) {
  size_t i = (size_t)blockIdx.x * blockDim.x + threadIdx.x;
  size_t stride = (size_t)gridDim.x * blockDim.x;
  for (; i < n; i += stride) p[i] = v;
}

// ---------------- tiled fp32 GEMM with fused BN scale / bias / act / skip ----------------
// C = act(colscale⊙A @ B + bias); if res: C = g*C + (1-g)*(resscale⊙res + resshift)

__global__ __launch_bounds__(256) void gemm_tile(
    const float* __restrict__ A, int lda, const float* __restrict__ colscale,
    const float* __restrict__ B, int ldb,
    const float* __restrict__ bias,
    float* __restrict__ Cmat, int ldc,
    int M, int N, int K, int act,
    const float* __restrict__ res, int ldres,
    const float* __restrict__ resscale, const float* __restrict__ resshift,
    const float* __restrict__ skip_ptr, int skip_idx)
{
  __shared__ __align__(16) float As[16][68];
  __shared__ __align__(16) float Bs[16][68];
  int tid = threadIdx.x;
  int tx = tid & 15, ty = tid >> 4;
  int row0 = blockIdx.x * 64, col0 = blockIdx.y * 64;
  float acc[4][4] = {};
  for (int k0 = 0; k0 < K; k0 += 16) {
#pragma unroll
    for (int l = 0; l < 4; ++l) {
      int idx = tid + l * 256;
      int m = idx >> 4, kk = idx & 15;
      int gr = row0 + m;
      float a = (gr < M) ? A[(size_t)gr * lda + k0 + kk] : 0.f;
      if (colscale) a *= colscale[k0 + kk];
      As[kk][m] = a;
      int kb = idx >> 6, n = idx & 63;
      Bs[kb][n] = B[(size_t)(k0 + kb) * ldb + col0 + n];
    }
    __syncthreads();
#pragma unroll
    for (int kk = 0; kk < 16; ++kk) {
      float4 av = *(const float4*)&As[kk][ty * 4];
      float4 bv = *(const float4*)&Bs[kk][tx * 4];
      float a[4] = {av.x, av.y, av.z, av.w};
      float b[4] = {bv.x, bv.y, bv.z, bv.w};
#pragma unroll
      for (int i = 0; i < 4; ++i)
#pragma unroll
        for (int j = 0; j < 4; ++j)
          acc[i][j] = fmaf(a[i], b[j], acc[i][j]);
    }
    __syncthreads();
  }
  float g = 1.f;
  if (skip_ptr) g = 1.f / (1.f + expf(-skip_ptr[skip_idx]));
#pragma unroll
  for (int i = 0; i < 4; ++i) {
    int row = row0 + ty * 4 + i;
    if (row >= M) continue;
#pragma unroll
    for (int j = 0; j < 4; ++j) {
      int col = col0 + tx * 4 + j;
      float v = acc[i][j] + bias[col];
      if (act == 1) v = fmaxf(v, 0.f);
      if (res) {
        float rv = res[(size_t)row * ldres + col];
        if (resscale) rv = resscale[col] * rv + resshift[col];
        v = g * v + (1.f - g) * rv;
      }
      Cmat[(size_t)row * ldc + col] = v;
    }
  }
}

// ---------------- BN stats (sum + sumsq per column) ----------------

__global__ __launch_bounds__(256) void bn_stats(const float* __restrict__ y, int Nrows,
                                                float* __restrict__ stats) {
  __shared__ float sh1[256], sh2[256];
  int tid = threadIdx.x;
  int col = tid & 63;
  int q = tid >> 6;
  float s1 = 0.f, s2 = 0.f;
  for (int row = blockIdx.x * 4 + q; row < Nrows; row += gridDim.x * 4) {
    float v = y[(size_t)row * 64 + col];
    s1 += v;
    s2 += v * v;
  }
  sh1[tid] = s1;
  sh2[tid] = s2;
  __syncthreads();
  if (tid < 64) {
    s1 = sh1[tid] + sh1[tid + 64] + sh1[tid + 128] + sh1[tid + 192];
    s2 = sh2[tid] + sh2[tid + 64] + sh2[tid + 128] + sh2[tid + 192];
    atomicAdd(&stats[col], s1);
    atomicAdd(&stats[64 + col], s2);
  }
}

// stats -> per-column scale/shift (192 threads, 1 block)
__global__ void bn_finalize(const float* __restrict__ stats,
                            const float* __restrict__ gamma, const float* __restrict__ beta,
                            float* __restrict__ scale, float* __restrict__ shift) {
  int t = threadIdx.x;
  if (t >= 192) return;
  int ty = t >> 6, c = t & 63;
  float invN = (ty == 0) ? (1.f / NQ) : (ty == 1) ? (1.f / NA) : (1.f / NE);
  float mu = stats[ty * 128 + c] * invN;
  float var = stats[ty * 128 + 64 + c] * invN - mu * mu;
  float rs = rsqrtf(var + 1e-5f);
  float gm = gamma[ty * 64 + c];
  scale[t] = gm * rs;            // scale[ty*64+c]
  shift[t] = beta[ty * 64 + c] - gm * mu * rs;
}

// bias2[t][n] = b_kqv[t][n] + sum_k shift[t][k] * W_kqv[t][k][n]  (3 blocks x 192 thr)
__global__ void kqv_bias2(const float* __restrict__ b_kqv, const float* __restrict__ W_kqv,
                          const float* __restrict__ shift, float* __restrict__ bias2) {
  int t = blockIdx.x, n = threadIdx.x;
  float s = b_kqv[t * 192 + n];
  for (int k = 0; k < 64; ++k)
    s += shift[t * 64 + k] * W_kqv[(size_t)t * 64 * 192 + k * 192 + n];
  bias2[t * 192 + n] = s;
}

// ---------------- CSR build ----------------

__global__ void hist_kernel(const int* __restrict__ dst, int E,
                            unsigned* __restrict__ cnt, int base) {
  int i = blockIdx.x * blockDim.x + threadIdx.x;
  int stride = gridDim.x * blockDim.x;
  for (; i < E; i += stride) atomicAdd(&cnt[base + dst[i]], 1u);
}

// in-place exclusive scan of arr[0..n) in blocks of 1024; blocksums out
__global__ __launch_bounds__(256) void scan1(unsigned* __restrict__ arr, int n,
                                             unsigned* __restrict__ bsums) {
  __shared__ unsigned sh[256];
  int t = threadIdx.x;
  int base = blockIdx.x * 1024 + t * 4;
  unsigned v[4];
  unsigned s = 0;
#pragma unroll
  for (int j = 0; j < 4; ++j) {
    v[j] = (base + j < n) ? arr[base + j] : 0u;
    s += v[j];
  }
  sh[t] = s;
  __syncthreads();
  for (int off = 1; off < 256; off <<= 1) {
    unsigned x = (t >= off) ? sh[t - off] : 0u;
    __syncthreads();
    sh[t] += x;
    __syncthreads();
  }
  unsigned run = sh[t] - s;  // exclusive prefix for this thread
#pragma unroll
  for (int j = 0; j < 4; ++j) {
    if (base + j < n) arr[base + j] = run;
    run += v[j];
  }
  if (t == 255) bsums[blockIdx.x] = sh[255];
}

__global__ __launch_bounds__(256) void scan2(unsigned* __restrict__ bsums, int nb) {
  __shared__ unsigned sh[256];
  __shared__ unsigned carry;
  int t = threadIdx.x;
  if (t == 0) carry = 0;
  __syncthreads();
  for (int chunk = 0; chunk < nb; chunk += 256) {
    int i = chunk + t;
    unsigned v = (i < nb) ? bsums[i] : 0u;
    sh[t] = v;
    __syncthreads();
    for (int off = 1; off < 256; off <<= 1) {
      unsigned x = (t >= off) ? sh[t - off] : 0u;
      __syncthreads();
      sh[t] += x;
      __syncthreads();
    }
    unsigned inc = sh[t];
    unsigned c = carry;
    __syncthreads();
    if (i < nb) bsums[i] = c + inc - v;
    if (t == 255) carry = c + sh[255];
    __syncthreads();
  }
}

__global__ __launch_bounds__(256) void scan3(unsigned* __restrict__ arr,
                                             const unsigned* __restrict__ bsums,
                                             unsigned* __restrict__ cursor, int n) {
  int t = threadIdx.x;
  int base = blockIdx.x * 1024 + t * 4;
  unsigned add = bsums[blockIdx.x];
#pragma unroll
  for (int j = 0; j < 4; ++j) {
    int idx = base + j;
    if (idx < n) {
      unsigned r = arr[idx] + add;
      arr[idx] = r;
      cursor[idx] = r;
    }
  }
}

// scatter edges into CSR slots; payload = global src index | slot<<20
__global__ void scatter_kernel(const int* __restrict__ src, const int* __restrict__ dst, int E,
                               unsigned* __restrict__ cursor, unsigned* __restrict__ eidx,
                               int dstbase, int srcbase, unsigned slot) {
  int i = blockIdx.x * blockDim.x + threadIdx.x;
  int stride = gridDim.x * blockDim.x;
  for (; i < E; i += stride) {
    unsigned pos = atomicAdd(&cursor[dstbase + dst[i]], 1u);
    eidx[pos] = (unsigned)(srcbase + src[i]) | (slot << 20);
  }
}

// ---------------- per-dst q transform: qt_d = sum_f A_k[h,d,f] * q_f ----------------

__global__ __launch_bounds__(256) void qk_transform(
    const float* __restrict__ qin, int istride,
    float* __restrict__ qout, int ostride, int N,
    const float* __restrict__ Akr)
{
  int lane = threadIdx.x & 63;
  int h = lane >> 5, d = lane & 31;
  float ar[32];
#pragma unroll
  for (int ff = 0; ff < 32; ++ff) ar[ff] = Akr[h * 1024 + d * 32 + ff];
  int wid = (int)((blockIdx.x * blockDim.x + threadIdx.x) >> 6);
  int nw = (int)((gridDim.x * blockDim.x) >> 6);
  for (int n = wid; n < N; n += nw) {
    float q = qin[(size_t)n * istride + lane];
    float o = 0.f;
#pragma unroll
    for (int ff = 0; ff < 32; ++ff) o = fmaf(ar[ff], __shfl(q, ff, 32), o);
    qout[(size_t)n * ostride + lane] = o;
  }
}

// ---------------- gather: softmax-weighted aggregation per dst node ----------------
// one wave per dst node; vsum/denominator in registers; A_v applied once per rel;
// softmax normalize + exact GELU fused; single coalesced 256B store per node.

template <int NREL>
__global__ __launch_bounds__(256) void gather_kernel(
    int N, int nodebase,
    const unsigned* __restrict__ row_start, const unsigned* __restrict__ row_end,
    const unsigned* __restrict__ eidx,
    const float* __restrict__ kqv,
    const float* __restrict__ qt0, int qt0stride,
    const float* __restrict__ qt1, int qt1stride,
    const float* __restrict__ Av0, const float* __restrict__ Av1,
    const float* __restrict__ prel0, const float* __restrict__ prel1,
    float* __restrict__ agg)
{
  int lane = threadIdx.x & 63;
  int h = lane >> 5, f = lane & 31;
  float av0[32], av1[32];
#pragma unroll
  for (int dd = 0; dd < 32; ++dd) av0[dd] = Av0[h * 1024 + dd * 32 + f];
  if (NREL == 2) {
#pragma unroll
    for (int dd = 0; dd < 32; ++dd) av1[dd] = Av1[h * 1024 + dd * 32 + f];
  }
  const float inv_sqrt_d = 0.17677669529663687f;
  float pr0 = prel0[h] * inv_sqrt_d;
  float pr1 = (NREL == 2) ? prel1[h] * inv_sqrt_d : 0.f;

  int wid = (int)((blockIdx.x * blockDim.x + threadIdx.x) >> 6);
  int nw = (int)((gridDim.x * blockDim.x) >> 6);
  for (int n = wid; n < N; n += nw) {
    float qt0v = qt0[(size_t)n * qt0stride + lane];
    float qt1v = (NREL == 2) ? qt1[(size_t)n * qt1stride + lane] : 0.f;
    unsigned i0 = row_start[nodebase + n];
    unsigned i1 = row_end[nodebase + n];
    float vs0 = 0.f, vs1 = 0.f, ss = 0.f;
    for (unsigned i = i0; i < i1; ++i) {
      unsigned p = eidx[i];
      unsigned srcg = p & 0xFFFFFu;
      bool r1 = (NREL == 2) && (p >> 20);
      float kval = kqv[(size_t)srcg * 192 + lane];
      float vval = kqv[(size_t)srcg * 192 + 128 + lane];
      float s = kval * (r1 ? qt1v : qt0v);
#pragma unroll
      for (int off = 16; off > 0; off >>= 1) s += __shfl_xor(s, off, 32);
      float w = expf(s * (r1 ? pr1 : pr0));
      ss += w;
      if (r1) vs1 += w * vval; else vs0 += w * vval;
    }
    float o = 0.f;
#pragma unroll
    for (int dd = 0; dd < 32; ++dd) o = fmaf(av0[dd], __shfl(vs0, dd, 32), o);
    if (NREL == 2) {
#pragma unroll
      for (int dd = 0; dd < 32; ++dd) o = fmaf(av1[dd], __shfl(vs1, dd, 32), o);
    }
    float val = (ss > 0.f) ? o / ss : 0.f;
    val = 0.5f * val * (1.f + erff(val * 0.70710678118654752f));
    agg[((size_t)(nodebase + n)) * 64 + lane] = val;
  }
}

// ---------------- final predictions ----------------

__global__ void pred_kernel(const int* __restrict__ qi, const int* __restrict__ ai, int Np,
                            const float* __restrict__ zq, const float* __restrict__ za,
                            float* __restrict__ outp) {
  int i = blockIdx.x * blockDim.x + threadIdx.x;
  if (i >= Np) return;
  const float4* a = (const float4*)(zq + (size_t)qi[i] * 64);
  const float4* b = (const float4*)(za + (size_t)ai[i] * 64);
  float ssum = 0.f;
#pragma unroll
  for (int j = 0; j < 16; ++j) {
    float4 x = a[j], y = b[j];
    ssum += x.x * y.x + x.y * y.y + x.z * y.z + x.w * y.w;
  }
  outp[i] = ssum;
}

// ---------------- host launch ----------------

extern "C" void kernel_launch(void* const* d_in, const int* in_sizes, int n_in,
                              void* d_out, int out_size, void* d_ws, size_t ws_size,
                              hipStream_t stream) {
  const float* xq = (const float*)d_in[0];
  const float* xa = (const float*)d_in[1];
  const float* xe = (const float*)d_in[2];
  const int* e_e2q = (const int*)d_in[3];
  const int* e_e2e = (const int*)d_in[4];
  const int* e_e2a = (const int*)d_in[5];
  const int* e_q2a = (const int*)d_in[6];
  const int* pos_idx = (const int*)d_in[7];
  const int* neg_idx = (const int*)d_in[8];
  const float* W_in = (const float*)d_in[9];
  const float* b_in = (const float*)d_in[10];
  const float* bn_gamma = (const float*)d_in[11];
  const float* bn_beta = (const float*)d_in[12];
  const float* W_kqv = (const float*)d_in[13];
  const float* b_kqv = (const float*)d_in[14];
  const float* A_k = (const float*)d_in[15];
  const float* A_v = (const float*)d_in[16];
  const float* p_rel = (const float*)d_in[17];
  const float* W_out = (const float*)d_in[18];
  const float* b_out = (const float*)d_in[19];
  const float* skip = (const float*)d_in[20];
  float* out = (float*)d_out;

  float* ws = (float*)d_ws;
  size_t off = 0;
  float* y_all = ws;            off += (size_t)NT_TOTAL * 64;
  float* kqv_all = ws + off;    off += (size_t)NT_TOTAL * 192;
  float* agg_all = ws + off;    off += (size_t)NT_TOTAL * 64;
  float* qt3buf = ws + off;     off += (size_t)NA * 64;
  float* stats = ws + off;      off += 384;   // 3*128
  float* scale = ws + off;      off += 192;
  float* shift = ws + off;      off += 192;
  float* bias2 = ws + off;      off += 576;
  unsigned* row_start = (unsigned*)(ws + off); off += NT_TOTAL;
  unsigned* cursor = (unsigned*)(ws + off);    off += NT_TOTAL;
  unsigned* bsums = (unsigned*)(ws + off);     off += 1024;
  unsigned* eidx = (unsigned*)(ws + off);      off += E_TOTAL;

  const int Ns[3] = {NQ, NA, NE};
  const float* xs[3] = {xq, xa, xe};
  // node order in unified space / buffers: [q, a, e]
  float* ybase[3] = {y_all, y_all + (size_t)NQ * 64, y_all + (size_t)(NQ + NA) * 64};
  float* kqvbase[3] = {kqv_all, kqv_all + (size_t)NQ * 192, kqv_all + (size_t)(NQ + NA) * 192};
  float* aggbase[3] = {agg_all, agg_all + (size_t)NQ * 64, agg_all + (size_t)(NQ + NA) * 64};
  float* zq_out = out + (N_POS + N_NEG);
  float* zbase[3] = {zq_out, zq_out + (size_t)NQ * 64, zq_out + (size_t)(NQ + NA) * 64};

  // zero stats + CSR counts (0.0f == all-zero bits)
  fill_kernel<<<dim3(8), dim3(256), 0, stream>>>(stats, 0.f, 384);
  fill_kernel<<<dim3(128), dim3(256), 0, stream>>>((float*)row_start, 0.f, NT_TOTAL);

  // ---- in-proj + relu -> y; BN stats ----
  for (int t = 0; t < 3; ++t) {
    dim3 g1((Ns[t] + 63) / 64, 1);
    gemm_tile<<<g1, 256, 0, stream>>>(xs[t], F_IN, nullptr,
                                      W_in + (size_t)t * F_IN * 64, 64, b_in + t * 64,
                                      ybase[t], 64, Ns[t], 64, F_IN, 1,
                                      nullptr, 0, nullptr, nullptr, nullptr, 0);
    bn_stats<<<dim3(512), dim3(256), 0, stream>>>(ybase[t], Ns[t], stats + t * 128);
  }
  bn_finalize<<<dim3(1), dim3(192), 0, stream>>>(stats, bn_gamma, bn_beta, scale, shift);
  kqv_bias2<<<dim3(3), dim3(192), 0, stream>>>(b_kqv, W_kqv, shift, bias2);

  // ---- kqv projection with BN folded in ----
  for (int t = 0; t < 3; ++t) {
    dim3 g2((Ns[t] + 63) / 64, 3);
    gemm_tile<<<g2, 256, 0, stream>>>(ybase[t], 64, scale + t * 64,
                                      W_kqv + (size_t)t * 64 * 192, 192, bias2 + t * 192,
                                      kqvbase[t], 192, Ns[t], 192, 64, 0,
                                      nullptr, 0, nullptr, nullptr, nullptr, 0);
  }

  // ---- CSR build ----
  struct Rel { const int* ei; int E; int srcbase; int dstbase; unsigned slot; };
  Rel rels[4] = {{e_e2q, E_E2Q, BASE_E, BASE_Q, 0u},
                 {e_e2e, E_E2E, BASE_E, BASE_E, 0u},
                 {e_e2a, E_E2A, BASE_E, BASE_A, 0u},
                 {e_q2a, E_Q2A, BASE_Q, BASE_A, 1u}};
  for (int r = 0; r < 4; ++r) {
    int blocks = (rels[r].E + 255) / 256; if (blocks > 2048) blocks = 2048;
    hist_kernel<<<dim3(blocks), dim3(256), 0, stream>>>(rels[r].ei + rels[r].E, rels[r].E,
                                                        row_start, rels[r].dstbase);
  }
  scan1<<<dim3(NBLK_SCAN), dim3(256), 0, stream>>>(row_start, NT_TOTAL, bsums);
  scan2<<<dim3(1), dim3(256), 0, stream>>>(bsums, NBLK_SCAN);
  scan3<<<dim3(NBLK_SCAN), dim3(256), 0, stream>>>(row_start, bsums, cursor, NT_TOTAL);
  for (int r = 0; r < 4; ++r) {
    int blocks = (rels[r].E + 255) / 256; if (blocks > 2048) blocks = 2048;
    scatter_kernel<<<dim3(blocks), dim3(256), 0, stream>>>(
        rels[r].ei, rels[r].ei + rels[r].E, rels[r].E, cursor, eidx,
        rels[r].dstbase, rels[r].srcbase, rels[r].slot);
  }

  // ---- per-dst q transforms (qt = A_k q). r3 first (reads a-type q before r2
  // overwrites it in place); r0/r1/r2 transform the kqv q-slot in place. ----
  {
    int blocks;
    blocks = (NA + 3) / 4;
    qk_transform<<<dim3(blocks), dim3(256), 0, stream>>>(kqvbase[1] + 64, 192, qt3buf, 64, NA,
                                                         A_k + 3 * 2048);
    qk_transform<<<dim3(blocks), dim3(256), 0, stream>>>(kqvbase[1] + 64, 192, kqvbase[1] + 64,
                                                         192, NA, A_k + 2 * 2048);
    blocks = (NQ + 3) / 4;
    qk_transform<<<dim3(blocks), dim3(256), 0, stream>>>(kqvbase[0] + 64, 192, kqvbase[0] + 64,
                                                         192, NQ, A_k + 0 * 2048);
    blocks = 2048;
    qk_transform<<<dim3(blocks), dim3(256), 0, stream>>>(kqvbase[2] + 64, 192, kqvbase[2] + 64,
                                                         192, NE, A_k + 1 * 2048);
  }

  // ---- gather (atomic-free aggregation + softmax + GELU) ----
  {
    int blocks;
    blocks = (NQ + 3) / 4;
    gather_kernel<1><<<dim3(blocks), dim3(256), 0, stream>>>(
        NQ, BASE_Q, row_start, cursor, eidx, kqv_all,
        kqvbase[0] + 64, 192, nullptr, 0,
        A_v + 0 * 2048, A_v + 0 * 2048, p_rel + 0, p_rel + 0, agg_all);
    blocks = 4096;
    gather_kernel<1><<<dim3(blocks), dim3(256), 0, stream>>>(
        NE, BASE_E, row_start, cursor, eidx, kqv_all,
        kqvbase[2] + 64, 192, nullptr, 0,
        A_v + 1 * 2048, A_v + 1 * 2048, p_rel + 2, p_rel + 2, agg_all);
    blocks = (NA + 3) / 4;
    gather_kernel<2><<<dim3(blocks), dim3(256), 0, stream>>>(
        NA, BASE_A, row_start, cursor, eidx, kqv_all,
        kqvbase[1] + 64, 192, qt3buf, 64,
        A_v + 2 * 2048, A_v + 3 * 2048, p_rel + 4, p_rel + 6, agg_all);
  }

  // ---- out projection + skip blend (h = scale*y+shift computed on the fly) ----
  for (int t = 0; t < 3; ++t) {
    dim3 g3((Ns[t] + 63) / 64, 1);
    gemm_tile<<<g3, 256, 0, stream>>>(aggbase[t], 64, nullptr,
                                      W_out + (size_t)t * 64 * 64, 64, b_out + t * 64,
                                      zbase[t], 64, Ns[t], 64, 64, 0,
                                      ybase[t], 64, scale + t * 64, shift + t * 64, skip, t);
  }

  // ---- predictions ----
  pred_kernel<<<dim3((N_POS + 255) / 256), dim3(256), 0, stream>>>(
      pos_idx, pos_idx + N_POS, N_POS, zbase[0], zbase[1], out);
  pred_kernel<<<dim3((N_NEG + 255) / 256), dim3(256), 0, stream>>>(
      neg_idx, neg_idx + N_NEG, N_NEG, zbase[0], zbase[1], out + N_POS);
}

// Round 5
// 1393.313 us; speedup vs baseline: 1.8208x; 1.2951x over previous
//
#include <hip/hip_runtime.h>
#include <hip/hip_bf16.h>
#include <math.h>

#define NQ 8192
#define NA 32768
#define NE 500000
#define F_IN 128
#define E_E2Q 131072
#define E_E2E 800000
#define E_E2A 262144
#define E_Q2A 32768
#define N_POS 8192
#define N_NEG 24576

#define NT_TOTAL (NQ + NA + NE)                      // 540960
#define E_TOTAL (E_E2Q + E_E2E + E_E2A + E_Q2A)      // 1225984
#define NBLK_SCAN ((NT_TOTAL + 1023) / 1024)         // 529
#define CDIV(a, b) (((a) + (b) - 1) / (b))

// dst node index space: [question: 0) [answer: NQ) [entity: NQ+NA)
#define BASE_Q 0
#define BASE_A NQ
#define BASE_E (NQ + NA)
// src (kqv_qe) index space: [question: 0) [entity: NQ)
#define SRC_Q 0
#define SRC_E NQ

// ---------------- utility ----------------

__global__ void fill_kernel(float* __restrict__ p, float v, size_t n) {
  size_t i = (size_t)blockIdx.x * blockDim.x + threadIdx.x;
  size_t stride = (size_t)gridDim.x * blockDim.x;
  for (; i < n; i += stride) p[i] = v;
}

// ---------------- fp32 GEMM, 8xTN microtile, full-N block ----------------
// C[M,BN] = act(colscale⊙A[M,K] @ B[K,BN] + bias)
// ACT: 0 none, 1 relu, 2 skip-blend: C = g*C + (1-g)*(resscale⊙res + resshift)

template <int BM, int BN, int TM, int TN, int KTOT, int ACT>
__global__ __launch_bounds__((BM / TM) * (BN / TN)) void gemm_fp32(
    const float* __restrict__ A, int lda, const float* __restrict__ colscale,
    const float* __restrict__ B, int ldb,
    const float* __restrict__ bias,
    float* __restrict__ C, int ldc, int M,
    const float* __restrict__ res, int ldres,
    const float* __restrict__ resscale, const float* __restrict__ resshift,
    const float* __restrict__ skip_ptr, int skip_idx)
{
  constexpr int NTHR = (BM / TM) * (BN / TN);
  constexpr int CT = BN / TN;
  __shared__ __align__(16) float As[16][BM + 4];
  __shared__ __align__(16) float Bs[16][BN + 4];
  int tid = threadIdx.x;
  int tx = tid % CT, ty = tid / CT;
  int row0 = blockIdx.x * BM;
  float acc[TM][TN] = {};
  for (int k0 = 0; k0 < KTOT; k0 += 16) {
    // stage A (float4 per thread, transpose into As[k][m])
    for (int i4 = tid; i4 < BM * 4; i4 += NTHR) {
      int m = i4 >> 2, kq = (i4 & 3) * 4;
      int gr = row0 + m;
      float4 a4 = make_float4(0.f, 0.f, 0.f, 0.f);
      if (gr < M) a4 = *(const float4*)&A[(size_t)gr * lda + k0 + kq];
      if (colscale) {
        float4 cs = *(const float4*)&colscale[k0 + kq];
        a4.x *= cs.x; a4.y *= cs.y; a4.z *= cs.z; a4.w *= cs.w;
      }
      As[kq + 0][m] = a4.x; As[kq + 1][m] = a4.y;
      As[kq + 2][m] = a4.z; As[kq + 3][m] = a4.w;
    }
    // stage B (float4, direct)
    for (int i4 = tid; i4 < BN * 4; i4 += NTHR) {
      int kb = i4 / (BN / 4), n4 = (i4 % (BN / 4)) * 4;
      *(float4*)&Bs[kb][n4] = *(const float4*)&B[(size_t)(k0 + kb) * ldb + n4];
    }
    __syncthreads();
#pragma unroll
    for (int kk = 0; kk < 16; ++kk) {
      float a[TM], b[TN];
#pragma unroll
      for (int i = 0; i < TM; i += 4) {
        float4 t4 = *(const float4*)&As[kk][ty * TM + i];
        a[i] = t4.x; a[i + 1] = t4.y; a[i + 2] = t4.z; a[i + 3] = t4.w;
      }
#pragma unroll
      for (int j = 0; j < TN; j += 4) {
        float4 t4 = *(const float4*)&Bs[kk][tx * TN + j];
        b[j] = t4.x; b[j + 1] = t4.y; b[j + 2] = t4.z; b[j + 3] = t4.w;
      }
#pragma unroll
      for (int i = 0; i < TM; ++i)
#pragma unroll
        for (int j = 0; j < TN; ++j)
          acc[i][j] = fmaf(a[i], b[j], acc[i][j]);
    }
    __syncthreads();
  }
  // epilogue
  float g = 1.f, gb = 0.f;
  if (ACT == 2) { g = 1.f / (1.f + expf(-skip_ptr[skip_idx])); gb = 1.f - g; }
  float bia[TN], rsc[TN], rsh[TN];
#pragma unroll
  for (int j = 0; j < TN; j += 4) {
    float4 t4 = *(const float4*)&bias[tx * TN + j];
    bia[j] = t4.x; bia[j + 1] = t4.y; bia[j + 2] = t4.z; bia[j + 3] = t4.w;
  }
  if (ACT == 2) {
#pragma unroll
    for (int j = 0; j < TN; j += 4) {
      float4 t4 = *(const float4*)&resscale[tx * TN + j];
      rsc[j] = t4.x; rsc[j + 1] = t4.y; rsc[j + 2] = t4.z; rsc[j + 3] = t4.w;
      float4 u4 = *(const float4*)&resshift[tx * TN + j];
      rsh[j] = u4.x; rsh[j + 1] = u4.y; rsh[j + 2] = u4.z; rsh[j + 3] = u4.w;
    }
  }
#pragma unroll
  for (int i = 0; i < TM; ++i) {
    int row = row0 + ty * TM + i;
    if (row >= M) break;
#pragma unroll
    for (int j = 0; j < TN; j += 4) {
      float v[4];
      float4 rv = make_float4(0.f, 0.f, 0.f, 0.f);
      if (ACT == 2) rv = *(const float4*)&res[(size_t)row * ldres + tx * TN + j];
      float rvv[4] = {rv.x, rv.y, rv.z, rv.w};
#pragma unroll
      for (int c = 0; c < 4; ++c) {
        float x = acc[i][j + c] + bia[j + c];
        if (ACT == 1) x = fmaxf(x, 0.f);
        if (ACT == 2) x = g * x + gb * (rsc[j + c] * rvv[c] + rsh[j + c]);
        v[c] = x;
      }
      *(float4*)&C[(size_t)row * ldc + tx * TN + j] =
          make_float4(v[0], v[1], v[2], v[3]);
    }
  }
}

// ---------------- BN stats (sum + sumsq per column) ----------------

__global__ __launch_bounds__(256) void bn_stats(const float* __restrict__ y, int Nrows,
                                                float* __restrict__ stats) {
  __shared__ float sh1[256], sh2[256];
  int tid = threadIdx.x;
  int col = tid & 63;
  int q = tid >> 6;
  float s1 = 0.f, s2 = 0.f;
  for (int row = blockIdx.x * 4 + q; row < Nrows; row += gridDim.x * 4) {
    float v = y[(size_t)row * 64 + col];
    s1 += v;
    s2 += v * v;
  }
  sh1[tid] = s1;
  sh2[tid] = s2;
  __syncthreads();
  if (tid < 64) {
    s1 = sh1[tid] + sh1[tid + 64] + sh1[tid + 128] + sh1[tid + 192];
    s2 = sh2[tid] + sh2[tid + 64] + sh2[tid + 128] + sh2[tid + 192];
    atomicAdd(&stats[col], s1);
    atomicAdd(&stats[64 + col], s2);
  }
}

__global__ void bn_finalize(const float* __restrict__ stats,
                            const float* __restrict__ gamma, const float* __restrict__ beta,
                            float* __restrict__ scale, float* __restrict__ shift) {
  int t = threadIdx.x;
  if (t >= 192) return;
  int ty = t >> 6, c = t & 63;
  float invN = (ty == 0) ? (1.f / NQ) : (ty == 1) ? (1.f / NA) : (1.f / NE);
  float mu = stats[ty * 128 + c] * invN;
  float var = stats[ty * 128 + 64 + c] * invN - mu * mu;
  float rs = rsqrtf(var + 1e-5f);
  float gm = gamma[ty * 64 + c];
  scale[t] = gm * rs;
  shift[t] = beta[ty * 64 + c] - gm * mu * rs;
}

// bias2[t][n] = b_kqv[t][n] + sum_k shift[t][k] * W_kqv[t][k][n]
__global__ void kqv_bias2(const float* __restrict__ b_kqv, const float* __restrict__ W_kqv,
                          const float* __restrict__ shift, float* __restrict__ bias2) {
  int t = blockIdx.x, n = threadIdx.x;
  float s = b_kqv[t * 192 + n];
  for (int k = 0; k < 64; ++k)
    s += shift[t * 64 + k] * W_kqv[(size_t)t * 64 * 192 + k * 192 + n];
  bias2[t * 192 + n] = s;
}

// ---------------- weight prep: fold A_k into q-columns of W_kqv ----------------
// Wq[64][192] = [k | qt(rel0) | v]          (question dst / src)
// We[64][192] = [k | qt(rel1) | v]          (entity dst / src)
// Wa[64][128] = [qt(rel2) | qt(rel3)]       (answer dst only)
// bias_big[512] laid out [q:192 | e:192 | a:128], from bias2 (BN-folded).

__global__ void wprep(const float* __restrict__ W_kqv, const float* __restrict__ bias2,
                      const float* __restrict__ A_k,
                      float* __restrict__ Wq, float* __restrict__ We, float* __restrict__ Wa,
                      float* __restrict__ bias_big) {
  int j = blockIdx.x;   // 0..511
  int c = threadIdx.x;  // 0..63
  int t, jj, ldw, bofs;
  float* W;
  if (j < 192)      { t = 0; jj = j;       W = Wq; ldw = 192; bofs = 0; }
  else if (j < 384) { t = 2; jj = j - 192; W = We; ldw = 192; bofs = 192; }
  else              { t = 1; jj = j - 384; W = Wa; ldw = 128; bofs = 384; }
  const float* Wt = W_kqv + (size_t)t * 64 * 192;
  const float* b2 = bias2 + t * 192;
  bool isqt = false;
  int rel = 0, h = 0, d = 0;
  if (t == 1) { isqt = true; rel = (jj < 64) ? 2 : 3; h = (jj & 63) >> 5; d = jj & 31; }
  else if (jj >= 64 && jj < 128) {
    isqt = true; rel = (t == 0) ? 0 : 1; h = (jj - 64) >> 5; d = jj & 31;
  }
  float wv, bv;
  if (isqt) {
    const float* Ar = A_k + ((size_t)rel * 2048 + h * 1024 + d * 32);
    float s = 0.f, sb = 0.f;
    for (int ff = 0; ff < 32; ++ff) {
      float a = Ar[ff];
      s = fmaf(a, Wt[(size_t)c * 192 + 64 + h * 32 + ff], s);
      sb = fmaf(a, b2[64 + h * 32 + ff], sb);
    }
    wv = s; bv = sb;
  } else {
    wv = Wt[(size_t)c * 192 + jj];
    bv = b2[jj];
  }
  W[(size_t)c * ldw + jj] = wv;
  if (c == 0) bias_big[bofs + jj] = bv;
}

// ---------------- CSR build ----------------

__global__ void hist_kernel(const int* __restrict__ dst, int E,
                            unsigned* __restrict__ cnt, int base) {
  int i = blockIdx.x * blockDim.x + threadIdx.x;
  int stride = gridDim.x * blockDim.x;
  for (; i < E; i += stride) atomicAdd(&cnt[base + dst[i]], 1u);
}

__global__ __launch_bounds__(256) void scan1(unsigned* __restrict__ arr, int n,
                                             unsigned* __restrict__ bsums) {
  __shared__ unsigned sh[256];
  int t = threadIdx.x;
  int base = blockIdx.x * 1024 + t * 4;
  unsigned v[4];
  unsigned s = 0;
#pragma unroll
  for (int j = 0; j < 4; ++j) {
    v[j] = (base + j < n) ? arr[base + j] : 0u;
    s += v[j];
  }
  sh[t] = s;
  __syncthreads();
  for (int off = 1; off < 256; off <<= 1) {
    unsigned x = (t >= off) ? sh[t - off] : 0u;
    __syncthreads();
    sh[t] += x;
    __syncthreads();
  }
  unsigned run = sh[t] - s;
#pragma unroll
  for (int j = 0; j < 4; ++j) {
    if (base + j < n) arr[base + j] = run;
    run += v[j];
  }
  if (t == 255) bsums[blockIdx.x] = sh[255];
}

__global__ __launch_bounds__(256) void scan2(unsigned* __restrict__ bsums, int nb) {
  __shared__ unsigned sh[256];
  __shared__ unsigned carry;
  int t = threadIdx.x;
  if (t == 0) carry = 0;
  __syncthreads();
  for (int chunk = 0; chunk < nb; chunk += 256) {
    int i = chunk + t;
    unsigned v = (i < nb) ? bsums[i] : 0u;
    sh[t] = v;
    __syncthreads();
    for (int off = 1; off < 256; off <<= 1) {
      unsigned x = (t >= off) ? sh[t - off] : 0u;
      __syncthreads();
      sh[t] += x;
      __syncthreads();
    }
    unsigned inc = sh[t];
    unsigned c = carry;
    __syncthreads();
    if (i < nb) bsums[i] = c + inc - v;
    if (t == 255) carry = c + sh[255];
    __syncthreads();
  }
}

__global__ __launch_bounds__(256) void scan3(unsigned* __restrict__ arr,
                                             const unsigned* __restrict__ bsums,
                                             unsigned* __restrict__ cursor, int n) {
  int t = threadIdx.x;
  int base = blockIdx.x * 1024 + t * 4;
  unsigned add = bsums[blockIdx.x];
#pragma unroll
  for (int j = 0; j < 4; ++j) {
    int idx = base + j;
    if (idx < n) {
      unsigned r = arr[idx] + add;
      arr[idx] = r;
      cursor[idx] = r;
    }
  }
}

// payload = src index in kqv_qe space | slot<<20
__global__ void scatter_kernel(const int* __restrict__ src, const int* __restrict__ dst, int E,
                               unsigned* __restrict__ cursor, unsigned* __restrict__ eidx,
                               int dstbase, int srcbase, unsigned slot) {
  int i = blockIdx.x * blockDim.x + threadIdx.x;
  int stride = gridDim.x * blockDim.x;
  for (; i < E; i += stride) {
    unsigned pos = atomicAdd(&cursor[dstbase + dst[i]], 1u);
    eidx[pos] = (unsigned)(srcbase + src[i]) | (slot << 20);
  }
}

// ---------------- gather: softmax-weighted aggregation per dst node ----------------

template <int NREL>
__global__ __launch_bounds__(256) void gather_kernel(
    int N, int nodebase,
    const unsigned* __restrict__ row_start, const unsigned* __restrict__ row_end,
    const unsigned* __restrict__ eidx,
    const float* __restrict__ kqv_src,                 // stride 192: k@0, v@128
    const float* __restrict__ qtbase, int qtstride, int qt1off,
    const float* __restrict__ Av0, const float* __restrict__ Av1,
    const float* __restrict__ prel0, const float* __restrict__ prel1,
    float* __restrict__ agg)
{
  int lane = threadIdx.x & 63;
  int h = lane >> 5, f = lane & 31;
  float av0[32], av1[32];
#pragma unroll
  for (int dd = 0; dd < 32; ++dd) av0[dd] = Av0[h * 1024 + dd * 32 + f];
  if (NREL == 2) {
#pragma unroll
    for (int dd = 0; dd < 32; ++dd) av1[dd] = Av1[h * 1024 + dd * 32 + f];
  }
  const float isd = 0.17677669529663687f;
  float pr0 = prel0[h] * isd;
  float pr1 = (NREL == 2) ? prel1[h] * isd : 0.f;

  int wid = (int)((blockIdx.x * blockDim.x + threadIdx.x) >> 6);
  int nw = (int)((gridDim.x * blockDim.x) >> 6);
  for (int n = wid; n < N; n += nw) {
    float qt0v = qtbase[(size_t)n * qtstride + lane];
    float qt1v = (NREL == 2) ? qtbase[(size_t)n * qtstride + qt1off + lane] : 0.f;
    unsigned i0 = row_start[nodebase + n];
    unsigned i1 = row_end[nodebase + n];
    float vs0 = 0.f, vs1 = 0.f, ss = 0.f;
    unsigned i = i0;
    for (; i + 2 <= i1; i += 2) {   // 2-edge unroll: two independent chains
      unsigned p1 = eidx[i], p2 = eidx[i + 1];
      unsigned s1i = p1 & 0xFFFFFu, s2i = p2 & 0xFFFFFu;
      bool r1 = (NREL == 2) && (p1 >> 20);
      bool r2 = (NREL == 2) && (p2 >> 20);
      float k1 = kqv_src[(size_t)s1i * 192 + lane];
      float v1 = kqv_src[(size_t)s1i * 192 + 128 + lane];
      float k2 = kqv_src[(size_t)s2i * 192 + lane];
      float v2 = kqv_src[(size_t)s2i * 192 + 128 + lane];
      float sa = k1 * (r1 ? qt1v : qt0v);
      float sb = k2 * (r2 ? qt1v : qt0v);
#pragma unroll
      for (int off = 16; off > 0; off >>= 1) {
        sa += __shfl_xor(sa, off, 32);
        sb += __shfl_xor(sb, off, 32);
      }
      float w1 = expf(sa * (r1 ? pr1 : pr0));
      float w2 = expf(sb * (r2 ? pr1 : pr0));
      ss += w1 + w2;
      if (NREL == 2) {
        float wv1 = w1 * v1, wv2 = w2 * v2;
        vs0 += (r1 ? 0.f : wv1) + (r2 ? 0.f : wv2);
        vs1 += (r1 ? wv1 : 0.f) + (r2 ? wv2 : 0.f);
      } else {
        vs0 = fmaf(w1, v1, vs0);
        vs0 = fmaf(w2, v2, vs0);
      }
    }
    if (i < i1) {
      unsigned p1 = eidx[i];
      unsigned s1i = p1 & 0xFFFFFu;
      bool r1 = (NREL == 2) && (p1 >> 20);
      float k1 = kqv_src[(size_t)s1i * 192 + lane];
      float v1 = kqv_src[(size_t)s1i * 192 + 128 + lane];
      float sa = k1 * (r1 ? qt1v : qt0v);
#pragma unroll
      for (int off = 16; off > 0; off >>= 1) sa += __shfl_xor(sa, off, 32);
      float w1 = expf(sa * (r1 ? pr1 : pr0));
      ss += w1;
      if (NREL == 2) {
        float wv1 = w1 * v1;
        vs0 += r1 ? 0.f : wv1;
        vs1 += r1 ? wv1 : 0.f;
      } else {
        vs0 = fmaf(w1, v1, vs0);
      }
    }
    // A_v transform: 4 parallel partial chains
    float o0 = 0.f, o1 = 0.f, o2 = 0.f, o3 = 0.f;
#pragma unroll
    for (int dd = 0; dd < 8; ++dd) {
      o0 = fmaf(av0[dd], __shfl(vs0, dd, 32), o0);
      o1 = fmaf(av0[dd + 8], __shfl(vs0, dd + 8, 32), o1);
      o2 = fmaf(av0[dd + 16], __shfl(vs0, dd + 16, 32), o2);
      o3 = fmaf(av0[dd + 24], __shfl(vs0, dd + 24, 32), o3);
    }
    if (NREL == 2) {
#pragma unroll
      for (int dd = 0; dd < 8; ++dd) {
        o0 = fmaf(av1[dd], __shfl(vs1, dd, 32), o0);
        o1 = fmaf(av1[dd + 8], __shfl(vs1, dd + 8, 32), o1);
        o2 = fmaf(av1[dd + 16], __shfl(vs1, dd + 16, 32), o2);
        o3 = fmaf(av1[dd + 24], __shfl(vs1, dd + 24, 32), o3);
      }
    }
    float o = (o0 + o1) + (o2 + o3);
    float val = (ss > 0.f) ? o / ss : 0.f;
    val = 0.5f * val * (1.f + erff(val * 0.70710678118654752f));
    agg[((size_t)(nodebase + n)) * 64 + lane] = val;
  }
}

// ---------------- final predictions ----------------

__global__ void pred_kernel(const int* __restrict__ qi, const int* __restrict__ ai, int Np,
                            const float* __restrict__ zq, const float* __restrict__ za,
                            float* __restrict__ outp) {
  int i = blockIdx.x * blockDim.x + threadIdx.x;
  if (i >= Np) return;
  const float4* a = (const float4*)(zq + (size_t)qi[i] * 64);
  const float4* b = (const float4*)(za + (size_t)ai[i] * 64);
  float ssum = 0.f;
#pragma unroll
  for (int j = 0; j < 16; ++j) {
    float4 x = a[j], y = b[j];
    ssum += x.x * y.x + x.y * y.y + x.z * y.z + x.w * y.w;
  }
  outp[i] = ssum;
}

// ---------------- host launch ----------------

extern "C" void kernel_launch(void* const* d_in, const int* in_sizes, int n_in,
                              void* d_out, int out_size, void* d_ws, size_t ws_size,
                              hipStream_t stream) {
  const float* xq = (const float*)d_in[0];
  const float* xa = (const float*)d_in[1];
  const float* xe = (const float*)d_in[2];
  const int* e_e2q = (const int*)d_in[3];
  const int* e_e2e = (const int*)d_in[4];
  const int* e_e2a = (const int*)d_in[5];
  const int* e_q2a = (const int*)d_in[6];
  const int* pos_idx = (const int*)d_in[7];
  const int* neg_idx = (const int*)d_in[8];
  const float* W_in = (const float*)d_in[9];
  const float* b_in = (const float*)d_in[10];
  const float* bn_gamma = (const float*)d_in[11];
  const float* bn_beta = (const float*)d_in[12];
  const float* W_kqv = (const float*)d_in[13];
  const float* b_kqv = (const float*)d_in[14];
  const float* A_k = (const float*)d_in[15];
  const float* A_v = (const float*)d_in[16];
  const float* p_rel = (const float*)d_in[17];
  const float* W_out = (const float*)d_in[18];
  const float* b_out = (const float*)d_in[19];
  const float* skip = (const float*)d_in[20];
  float* out = (float*)d_out;

  float* ws = (float*)d_ws;
  size_t off = 0;
  float* y_all = ws;           off += (size_t)NT_TOTAL * 64;
  float* kqv_qe = ws + off;    off += (size_t)(NQ + NE) * 192;
  float* kqv_a = ws + off;     off += (size_t)NA * 128;
  float* agg_all = ws + off;   off += (size_t)NT_TOTAL * 64;
  float* stats = ws + off;     off += 384;
  float* scale = ws + off;     off += 192;
  float* shift = ws + off;     off += 192;
  float* bias2 = ws + off;     off += 576;
  float* Wq = ws + off;        off += 64 * 192;
  float* We = ws + off;        off += 64 * 192;
  float* Wa = ws + off;        off += 64 * 128;
  float* bias_big = ws + off;  off += 512;
  unsigned* row_start = (unsigned*)(ws + off); off += NT_TOTAL;
  unsigned* cursor = (unsigned*)(ws + off);    off += NT_TOTAL;
  unsigned* bsums = (unsigned*)(ws + off);     off += 1024;
  unsigned* eidx = (unsigned*)(ws + off);      off += E_TOTAL;

  const int Ns[3] = {NQ, NA, NE};
  const float* xs[3] = {xq, xa, xe};
  float* ybase[3] = {y_all, y_all + (size_t)NQ * 64, y_all + (size_t)(NQ + NA) * 64};
  float* aggbase[3] = {agg_all, agg_all + (size_t)NQ * 64, agg_all + (size_t)(NQ + NA) * 64};
  float* kqv_q = kqv_qe;
  float* kqv_e = kqv_qe + (size_t)NQ * 192;
  float* zq_out = out + (N_POS + N_NEG);
  float* zbase[3] = {zq_out, zq_out + (size_t)NQ * 64, zq_out + (size_t)(NQ + NA) * 64};

  fill_kernel<<<dim3(8), dim3(256), 0, stream>>>(stats, 0.f, 384);
  fill_kernel<<<dim3(128), dim3(256), 0, stream>>>((float*)row_start, 0.f, NT_TOTAL);

  // ---- in-proj + relu -> y; BN stats ----
  for (int t = 0; t < 3; ++t) {
    gemm_fp32<256, 64, 8, 8, 128, 1><<<dim3(CDIV(Ns[t], 256)), dim3(256), 0, stream>>>(
        xs[t], F_IN, nullptr, W_in + (size_t)t * F_IN * 64, 64, b_in + t * 64,
        ybase[t], 64, Ns[t], nullptr, 0, nullptr, nullptr, nullptr, 0);
    bn_stats<<<dim3(512), dim3(256), 0, stream>>>(ybase[t], Ns[t], stats + t * 128);
  }
  bn_finalize<<<dim3(1), dim3(192), 0, stream>>>(stats, bn_gamma, bn_beta, scale, shift);
  kqv_bias2<<<dim3(3), dim3(192), 0, stream>>>(b_kqv, W_kqv, shift, bias2);
  wprep<<<dim3(512), dim3(64), 0, stream>>>(W_kqv, bias2, A_k, Wq, We, Wa, bias_big);

  // ---- kqv projections (BN + A_k folds inside) ----
  gemm_fp32<128, 192, 8, 12, 64, 0><<<dim3(CDIV(NQ, 128)), dim3(256), 0, stream>>>(
      ybase[0], 64, scale, Wq, 192, bias_big, kqv_q, 192, NQ,
      nullptr, 0, nullptr, nullptr, nullptr, 0);
  gemm_fp32<128, 192, 8, 12, 64, 0><<<dim3(CDIV(NE, 128)), dim3(256), 0, stream>>>(
      ybase[2], 64, scale + 128, We, 192, bias_big + 192, kqv_e, 192, NE,
      nullptr, 0, nullptr, nullptr, nullptr, 0);
  gemm_fp32<128, 128, 8, 8, 64, 0><<<dim3(CDIV(NA, 128)), dim3(256), 0, stream>>>(
      ybase[1], 64, scale + 64, Wa, 128, bias_big + 384, kqv_a, 128, NA,
      nullptr, 0, nullptr, nullptr, nullptr, 0);

  // ---- CSR build ----
  struct Rel { const int* ei; int E; int srcbase; int dstbase; unsigned slot; };
  Rel rels[4] = {{e_e2q, E_E2Q, SRC_E, BASE_Q, 0u},
                 {e_e2e, E_E2E, SRC_E, BASE_E, 0u},
                 {e_e2a, E_E2A, SRC_E, BASE_A, 0u},
                 {e_q2a, E_Q2A, SRC_Q, BASE_A, 1u}};
  for (int r = 0; r < 4; ++r) {
    int blocks = CDIV(rels[r].E, 256); if (blocks > 2048) blocks = 2048;
    hist_kernel<<<dim3(blocks), dim3(256), 0, stream>>>(rels[r].ei + rels[r].E, rels[r].E,
                                                        row_start, rels[r].dstbase);
  }
  scan1<<<dim3(NBLK_SCAN), dim3(256), 0, stream>>>(row_start, NT_TOTAL, bsums);
  scan2<<<dim3(1), dim3(256), 0, stream>>>(bsums, NBLK_SCAN);
  scan3<<<dim3(NBLK_SCAN), dim3(256), 0, stream>>>(row_start, bsums, cursor, NT_TOTAL);
  for (int r = 0; r < 4; ++r) {
    int blocks = CDIV(rels[r].E, 256); if (blocks > 2048) blocks = 2048;
    scatter_kernel<<<dim3(blocks), dim3(256), 0, stream>>>(
        rels[r].ei, rels[r].ei + rels[r].E, rels[r].E, cursor, eidx,
        rels[r].dstbase, rels[r].srcbase, rels[r].slot);
  }

  // ---- gathers (qt read directly from kqv rows; no transform passes) ----
  gather_kernel<1><<<dim3(CDIV(NQ, 4)), dim3(256), 0, stream>>>(
      NQ, BASE_Q, row_start, cursor, eidx, kqv_qe,
      kqv_q + 64, 192, 0, A_v, A_v, p_rel, p_rel, agg_all);
  gather_kernel<1><<<dim3(4096), dim3(256), 0, stream>>>(
      NE, BASE_E, row_start, cursor, eidx, kqv_qe,
      kqv_e + 64, 192, 0, A_v + 1 * 2048, A_v + 1 * 2048, p_rel + 2, p_rel + 2, agg_all);
  gather_kernel<2><<<dim3(CDIV(NA, 4)), dim3(256), 0, stream>>>(
      NA, BASE_A, row_start, cursor, eidx, kqv_qe,
      kqv_a, 128, 64, A_v + 2 * 2048, A_v + 3 * 2048, p_rel + 4, p_rel + 6, agg_all);

  // ---- out projection + skip blend ----
  for (int t = 0; t < 3; ++t) {
    gemm_fp32<256, 64, 8, 8, 64, 2><<<dim3(CDIV(Ns[t], 256)), dim3(256), 0, stream>>>(
        aggbase[t], 64, nullptr, W_out + (size_t)t * 64 * 64, 64, b_out + t * 64,
        zbase[t], 64, Ns[t], ybase[t], 64, scale + t * 64, shift + t * 64, skip, t);
  }

  // ---- predictions ----
  pred_kernel<<<dim3(CDIV(N_POS, 256)), dim3(256), 0, stream>>>(
      pos_idx, pos_idx + N_POS, N_POS, zbase[0], zbase[1], out);
  pred_kernel<<<dim3(CDIV(N_NEG, 256)), dim3(256), 0, stream>>>(
      neg_idx, neg_idx + N_NEG, N_NEG, zbase[0], zbase[1], out + N_POS);
}